// Round 1
// baseline (34953.638 us; speedup 1.0000x reference)
//
#include <hip/hip_runtime.h>
#include <cmath>

#define LEAK 0.95f
#define ILEAK 0.05f

// ---------------- Phase 1: u = x @ W_in^T (fp32 tiled GEMM) ----------------
// A = x [M=65536][K=512] row-major; B = W_in [N=1024][K=512] row-major.
// C = u [M][N] written into d_out (in-place staging for phase 2).
__global__ __launch_bounds__(256) void resv_gemm_uin(
    const float* __restrict__ A, const float* __restrict__ Bm,
    float* __restrict__ C, int M, int N, int K)
{
    __shared__ float As[16][68];
    __shared__ float Bs[16][68];
    const int tid = threadIdx.x;
    const int m0 = blockIdx.y * 64;
    const int n0 = blockIdx.x * 64;
    const int lm = tid >> 2;          // 0..63 (row within tile for loads)
    const int lk = (tid & 3) * 4;     // 0,4,8,12 (k within tile for loads)
    const int ty = tid >> 4;          // 0..15 (4 output rows)
    const int tx = tid & 15;          // 0..15 (4 output cols)

    float acc[4][4];
#pragma unroll
    for (int i = 0; i < 4; ++i)
#pragma unroll
        for (int j = 0; j < 4; ++j) acc[i][j] = 0.f;

    const float* Aptr = A + (size_t)(m0 + lm) * K + lk;
    const float* Bptr = Bm + (size_t)(n0 + lm) * K + lk;

    for (int k0 = 0; k0 < K; k0 += 16) {
        float4 av = *(const float4*)(Aptr + k0);
        float4 bv = *(const float4*)(Bptr + k0);
        __syncthreads();
        As[lk + 0][lm] = av.x; As[lk + 1][lm] = av.y;
        As[lk + 2][lm] = av.z; As[lk + 3][lm] = av.w;
        Bs[lk + 0][lm] = bv.x; Bs[lk + 1][lm] = bv.y;
        Bs[lk + 2][lm] = bv.z; Bs[lk + 3][lm] = bv.w;
        __syncthreads();
#pragma unroll
        for (int kk = 0; kk < 16; ++kk) {
            float4 a = *(const float4*)(&As[kk][ty * 4]);
            float4 b = *(const float4*)(&Bs[kk][tx * 4]);
            acc[0][0] += a.x * b.x; acc[0][1] += a.x * b.y; acc[0][2] += a.x * b.z; acc[0][3] += a.x * b.w;
            acc[1][0] += a.y * b.x; acc[1][1] += a.y * b.y; acc[1][2] += a.y * b.z; acc[1][3] += a.y * b.w;
            acc[2][0] += a.z * b.x; acc[2][1] += a.z * b.y; acc[2][2] += a.z * b.z; acc[2][3] += a.z * b.w;
            acc[3][0] += a.w * b.x; acc[3][1] += a.w * b.y; acc[3][2] += a.w * b.z; acc[3][3] += a.w * b.w;
        }
    }
    float* Cp = C + (size_t)(m0 + ty * 4) * N + n0 + tx * 4;
#pragma unroll
    for (int i = 0; i < 4; ++i) {
        float4 v = make_float4(acc[i][0], acc[i][1], acc[i][2], acc[i][3]);
        *(float4*)(Cp + (size_t)i * N) = v;
    }
}

// ---------------- Phase 2: leaky-tanh reservoir recurrence ----------------
// 256 wgs (1 per CU, forced by 154KB LDS). wg = (group g = bid&7, row-wg r = bid>>3).
// Group g owns batches b0=4g..4g+3 (independent across groups). Each wg holds
// W_res[32 rows][1024] fp32 resident in LDS, laid out in per-lane read order.
// Per step: stage prev[4][1024] (global->LDS), dot-products with W shared
// across the 4 batches, shfl + LDS reduce, tanh+leak, store new state + d_out,
// then a monotonic atomic barrier over the 32 wgs of the group.
__global__ __launch_bounds__(256, 1) void resv_recur(
    const float* __restrict__ Wres,   // [1024][1024]
    float* __restrict__ out,          // [32][2048][1024] (pre-filled with u)
    float* __restrict__ states,       // ws: [2][32][1024]
    unsigned* __restrict__ cnt)       // ws: [8] (zeroed per launch)
{
    constexpr int H = 1024, S = 2048;
    extern __shared__ float sm[];
    float* Wc    = sm;                          // 32768 floats (128 KB)
    float* prevL = sm + 32768;                  // 4096 floats  (16 KB)
    float* uL    = sm + 32768 + 4096;           // 2048 floats  (8 KB)
    float* red   = sm + 32768 + 4096 + 2048;    // 512 floats   (2 KB)

    const int gid = blockIdx.x;
    const int g  = gid & 7;
    const int r  = gid >> 3;
    const int h0 = r * 32;
    const int b0 = g * 4;
    const int tid = threadIdx.x;
    const int w  = tid >> 6;          // wave 0..3 = k-quarter
    const int l  = tid & 63;
    const int kb = w * 256 + (l >> 5) * 128;  // per-lane k base (128 k's)

    // ---- one-time: load W slice into LDS in compute (chunked) order ----
    for (int j = 0; j < 32; ++j) {
        int f   = tid + j * 256;      // 0..8191 : (row 0..31) x (256 float4/row)
        int rw  = f >> 8;
        int kf4 = f & 255;
        int k   = kf4 * 4;
        float4 v = *(const float4*)(Wres + (size_t)(h0 + rw) * H + k);
        int wq  = k >> 8;
        int rem = k & 255;
        int ks  = rem >> 7;
        int ii  = (rem & 127) >> 2;
        int lane  = (ks << 5) | rw;
        int chunk = ((ii * 4 + wq) << 6) | lane;
        *(float4*)(Wc + (size_t)chunk * 4) = v;
    }

    const int fb  = tid >> 5;   // finish: batch (tid<128)
    const int frw = tid & 31;   // finish: row

    unsigned p = 0;
    for (int t = 0; t < S; ++t) {
        if ((t & 15) == 0) {
            // stage u[t..t+15] for our (4 batches x 32 rows) slice; full 128B lines
            for (int c = tid; c < 512; c += 256) {
                int rw4 = c & 7, b = (c >> 3) & 3, tt = c >> 5;
                const float4* src =
                    (const float4*)(out + ((size_t)(b0 + b) * S + (t + tt)) * H + h0);
                ((float4*)uL)[(tt * 4 + b) * 8 + rw4] = src[rw4];
            }
        }
        { // stage prev[4][1024]
            const float4* src = (const float4*)(states + (size_t)p * 32 * H + (size_t)b0 * H);
            float4* dst = (float4*)prevL;
            for (int c = tid; c < 1024; c += 256) dst[c] = src[c];
        }
        __syncthreads();

        float acc0 = 0.f, acc1 = 0.f, acc2 = 0.f, acc3 = 0.f;
        const float4* Wp = (const float4*)Wc + (w * 64 + l);
        const float4* p0 = (const float4*)prevL + (kb >> 2);
        const float4* p1 = p0 + 256;
        const float4* p2 = p0 + 512;
        const float4* p3 = p0 + 768;
#pragma unroll
        for (int i = 0; i < 32; ++i) {
            float4 wv = Wp[(size_t)i * 256];
            float4 a0 = p0[i], a1 = p1[i], a2 = p2[i], a3 = p3[i];
            acc0 += wv.x * a0.x + wv.y * a0.y + wv.z * a0.z + wv.w * a0.w;
            acc1 += wv.x * a1.x + wv.y * a1.y + wv.z * a1.z + wv.w * a1.w;
            acc2 += wv.x * a2.x + wv.y * a2.y + wv.z * a2.z + wv.w * a2.w;
            acc3 += wv.x * a3.x + wv.y * a3.y + wv.z * a3.z + wv.w * a3.w;
        }
        // combine the two k-halves within the wave
        acc0 += __shfl_xor(acc0, 32, 64);
        acc1 += __shfl_xor(acc1, 32, 64);
        acc2 += __shfl_xor(acc2, 32, 64);
        acc3 += __shfl_xor(acc3, 32, 64);
        if (l < 32) {
            ((float4*)red)[w * 32 + (l & 31)] = make_float4(acc0, acc1, acc2, acc3);
        }
        __syncthreads();

        if (tid < 128) {
            float sum = red[(0  + frw) * 4 + fb] + red[(32 + frw) * 4 + fb]
                      + red[(64 + frw) * 4 + fb] + red[(96 + frw) * 4 + fb];
            float uv = uL[((t & 15) * 4 + fb) * 32 + frw];
            float pv = prevL[fb * H + h0 + frw];
            float ns = LEAK * tanhf(uv + sum) + ILEAK * pv;
            states[(size_t)(p ^ 1) * 32 * H + (size_t)(b0 + fb) * H + h0 + frw] = ns;
            out[((size_t)(b0 + fb) * S + t) * H + h0 + frw] = ns;
        }
        __syncthreads();   // barrier drains vmcnt(0): all wg stores are in L2

        if (t < S - 1) {
            if (tid == 0) {
                __threadfence();   // agent release (L2 writeback)
                __hip_atomic_fetch_add(&cnt[g], 1u, __ATOMIC_RELAXED, __HIP_MEMORY_SCOPE_AGENT);
                const unsigned target = 32u * (unsigned)(t + 1);
                while (__hip_atomic_load(&cnt[g], __ATOMIC_RELAXED, __HIP_MEMORY_SCOPE_AGENT) < target) {}
                __threadfence();   // agent acquire (invalidate)
            }
            __syncthreads();
        }
        p ^= 1;
    }
}

extern "C" void kernel_launch(void* const* d_in, const int* in_sizes, int n_in,
                              void* d_out, int out_size, void* d_ws, size_t ws_size,
                              hipStream_t stream)
{
    const float* x    = (const float*)d_in[0];   // [32][2048][512]
    const float* Win  = (const float*)d_in[1];   // [1024][512]
    const float* Wres = (const float*)d_in[2];   // [1024][1024]
    float* out = (float*)d_out;                  // [32][2048][1024]

    float* states = (float*)d_ws;                             // 2*32*1024*4 = 262144 B
    unsigned* cnt = (unsigned*)((char*)d_ws + 262144);        // 8 * 4 B

    // zero states (t=0 prev) and barrier counters every launch (graph-replay safe)
    hipMemsetAsync(d_ws, 0, 262144 + 64, stream);

    // phase 1: u = x @ W_in^T into d_out
    dim3 gemm_grid(1024 / 64, 65536 / 64);
    resv_gemm_uin<<<gemm_grid, 256, 0, stream>>>(x, Win, out, 65536, 1024, 512);

    // phase 2: recurrence (needs 154 KB dynamic LDS)
    constexpr int kLds = (32768 + 4096 + 2048 + 512) * 4;  // 157696 B
    hipFuncSetAttribute((const void*)resv_recur,
                        hipFuncAttributeMaxDynamicSharedMemorySize, kLds);
    resv_recur<<<dim3(256), dim3(256), kLds, stream>>>(Wres, out, states, cnt);
}

// Round 2
// 12649.846 us; speedup vs baseline: 2.7632x; 2.7632x over previous
//
#include <hip/hip_runtime.h>
#include <cmath>

#define LEAK 0.95f
#define ILEAK 0.05f

// ---------------- Phase 1: u = x @ W_in^T (fp32 tiled GEMM) ----------------
// A = x [M=65536][K=512] row-major; B = W_in [N=1024][K=512] row-major.
// C = u [M][N] written into d_out (in-place staging for phase 2).
__global__ __launch_bounds__(256) void resv_gemm_uin(
    const float* __restrict__ A, const float* __restrict__ Bm,
    float* __restrict__ C, int M, int N, int K)
{
    __shared__ float As[16][68];
    __shared__ float Bs[16][68];
    const int tid = threadIdx.x;
    const int m0 = blockIdx.y * 64;
    const int n0 = blockIdx.x * 64;
    const int lm = tid >> 2;          // 0..63 (row within tile for loads)
    const int lk = (tid & 3) * 4;     // 0,4,8,12 (k within tile for loads)
    const int ty = tid >> 4;          // 0..15 (4 output rows)
    const int tx = tid & 15;          // 0..15 (4 output cols)

    float acc[4][4];
#pragma unroll
    for (int i = 0; i < 4; ++i)
#pragma unroll
        for (int j = 0; j < 4; ++j) acc[i][j] = 0.f;

    const float* Aptr = A + (size_t)(m0 + lm) * K + lk;
    const float* Bptr = Bm + (size_t)(n0 + lm) * K + lk;

    for (int k0 = 0; k0 < K; k0 += 16) {
        float4 av = *(const float4*)(Aptr + k0);
        float4 bv = *(const float4*)(Bptr + k0);
        __syncthreads();
        As[lk + 0][lm] = av.x; As[lk + 1][lm] = av.y;
        As[lk + 2][lm] = av.z; As[lk + 3][lm] = av.w;
        Bs[lk + 0][lm] = bv.x; Bs[lk + 1][lm] = bv.y;
        Bs[lk + 2][lm] = bv.z; Bs[lk + 3][lm] = bv.w;
        __syncthreads();
#pragma unroll
        for (int kk = 0; kk < 16; ++kk) {
            float4 a = *(const float4*)(&As[kk][ty * 4]);
            float4 b = *(const float4*)(&Bs[kk][tx * 4]);
            acc[0][0] += a.x * b.x; acc[0][1] += a.x * b.y; acc[0][2] += a.x * b.z; acc[0][3] += a.x * b.w;
            acc[1][0] += a.y * b.x; acc[1][1] += a.y * b.y; acc[1][2] += a.y * b.z; acc[1][3] += a.y * b.w;
            acc[2][0] += a.z * b.x; acc[2][1] += a.z * b.y; acc[2][2] += a.z * b.z; acc[2][3] += a.z * b.w;
            acc[3][0] += a.w * b.x; acc[3][1] += a.w * b.y; acc[3][2] += a.w * b.z; acc[3][3] += a.w * b.w;
        }
    }
    float* Cp = C + (size_t)(m0 + ty * 4) * N + n0 + tx * 4;
#pragma unroll
    for (int i = 0; i < 4; ++i) {
        float4 v = make_float4(acc[i][0], acc[i][1], acc[i][2], acc[i][3]);
        *(float4*)(Cp + (size_t)i * N) = v;
    }
}

// ---------------- Phase 2: leaky-tanh reservoir recurrence ----------------
// 256 wgs (1 per CU, forced by 154KB LDS). wg = (group g = bid&7, row-wg r = bid>>3).
// Group g owns batches b0=4g..4g+3 (independent across groups). Each wg holds
// W_res[32 rows][1024] fp32 resident in LDS, laid out in per-lane read order.
//
// Cross-wg sync WITHOUT agent fences (no buffer_wbl2/buffer_inv): all
// cross-wg data (states, cnt) is touched ONLY via scope-annotated atomics:
//   - writes: __hip_atomic_store relaxed/agent (write-through, agent-visible)
//   - flag:   relaxed fetch_add after __syncthreads (barrier drains vmcnt(0),
//             so the sc1 stores are agent-visible before the flag bumps)
//   - reads:  64-bit relaxed/agent atomic loads (bypass stale L2, hit L3)
// No line of states/cnt is ever accessed non-annotated inside the kernel, so
// per-XCD L2 staleness cannot occur; kernel boundaries cover memset/GEMM.
__global__ __launch_bounds__(256, 1) void resv_recur(
    const float* __restrict__ Wres,   // [1024][1024]
    float* __restrict__ out,          // [32][2048][1024] (pre-filled with u)
    float* __restrict__ states,       // ws: [2][32][1024]
    unsigned* __restrict__ cnt)       // ws: [8] padded to 256B each (zeroed per launch)
{
    constexpr int H = 1024, S = 2048;
    extern __shared__ float sm[];
    float* Wc    = sm;                          // 32768 floats (128 KB)
    float* prevL = sm + 32768;                  // 4096 floats  (16 KB)
    float* uL    = sm + 32768 + 4096;           // 2048 floats  (8 KB)
    float* red   = sm + 32768 + 4096 + 2048;    // 512 floats   (2 KB)

    const int gid = blockIdx.x;
    const int g  = gid & 7;
    const int r  = gid >> 3;
    const int h0 = r * 32;
    const int b0 = g * 4;
    const int tid = threadIdx.x;
    const int w  = tid >> 6;          // wave 0..3 = k-quarter
    const int l  = tid & 63;
    const int kb = w * 256 + (l >> 5) * 128;  // per-lane k base (128 k's)

    // ---- one-time: load W slice into LDS in compute (chunked) order ----
    for (int j = 0; j < 32; ++j) {
        int f   = tid + j * 256;      // 0..8191 : (row 0..31) x (256 float4/row)
        int rw  = f >> 8;
        int kf4 = f & 255;
        int k   = kf4 * 4;
        float4 v = *(const float4*)(Wres + (size_t)(h0 + rw) * H + k);
        int wq  = k >> 8;
        int rem = k & 255;
        int ks  = rem >> 7;
        int ii  = (rem & 127) >> 2;
        int lane  = (ks << 5) | rw;
        int chunk = ((ii * 4 + wq) << 6) | lane;
        *(float4*)(Wc + (size_t)chunk * 4) = v;
    }

    const int fb  = tid >> 5;   // finish: batch (tid<128)
    const int frw = tid & 31;   // finish: row

    unsigned* flag = cnt + (size_t)g * 64;   // 256B-padded per-group counter

    unsigned p = 0;
    for (int t = 0; t < S; ++t) {
        if ((t & 15) == 0) {
            // stage u[t..t+15] for our (4 batches x 32 rows) slice; full 128B lines
            for (int c = tid; c < 512; c += 256) {
                int rw4 = c & 7, b = (c >> 3) & 3, tt = c >> 5;
                const float4* src =
                    (const float4*)(out + ((size_t)(b0 + b) * S + (t + tt)) * H + h0);
                ((float4*)uL)[(tt * 4 + b) * 8 + rw4] = src[rw4];
            }
        }
        { // stage prev[4][1024] via agent-scope atomic loads (L3-coherent)
            const unsigned long long* src =
                (const unsigned long long*)(states + (size_t)p * 32 * H + (size_t)b0 * H);
            unsigned long long* dst = (unsigned long long*)prevL;
            for (int c = tid; c < 2048; c += 256) {
                dst[c] = __hip_atomic_load(src + c, __ATOMIC_RELAXED,
                                           __HIP_MEMORY_SCOPE_AGENT);
            }
        }
        __syncthreads();

        float acc0 = 0.f, acc1 = 0.f, acc2 = 0.f, acc3 = 0.f;
        const float4* Wp = (const float4*)Wc + (w * 64 + l);
        const float4* p0 = (const float4*)prevL + (kb >> 2);
        const float4* p1 = p0 + 256;
        const float4* p2 = p0 + 512;
        const float4* p3 = p0 + 768;
#pragma unroll
        for (int i = 0; i < 32; ++i) {
            float4 wv = Wp[(size_t)i * 256];
            float4 a0 = p0[i], a1 = p1[i], a2 = p2[i], a3 = p3[i];
            acc0 += wv.x * a0.x + wv.y * a0.y + wv.z * a0.z + wv.w * a0.w;
            acc1 += wv.x * a1.x + wv.y * a1.y + wv.z * a1.z + wv.w * a1.w;
            acc2 += wv.x * a2.x + wv.y * a2.y + wv.z * a2.z + wv.w * a2.w;
            acc3 += wv.x * a3.x + wv.y * a3.y + wv.z * a3.z + wv.w * a3.w;
        }
        // combine the two k-halves within the wave
        acc0 += __shfl_xor(acc0, 32, 64);
        acc1 += __shfl_xor(acc1, 32, 64);
        acc2 += __shfl_xor(acc2, 32, 64);
        acc3 += __shfl_xor(acc3, 32, 64);
        if (l < 32) {
            ((float4*)red)[w * 32 + (l & 31)] = make_float4(acc0, acc1, acc2, acc3);
        }
        __syncthreads();

        if (tid < 128) {
            float sum = red[(0  + frw) * 4 + fb] + red[(32 + frw) * 4 + fb]
                      + red[(64 + frw) * 4 + fb] + red[(96 + frw) * 4 + fb];
            float uv = uL[((t & 15) * 4 + fb) * 32 + frw];
            float pv = prevL[fb * H + h0 + frw];
            float ns = LEAK * tanhf(uv + sum) + ILEAK * pv;
            // agent-annotated write-through store: visible at coherence point
            __hip_atomic_store(
                states + (size_t)(p ^ 1) * 32 * H + (size_t)(b0 + fb) * H + h0 + frw,
                ns, __ATOMIC_RELAXED, __HIP_MEMORY_SCOPE_AGENT);
            out[((size_t)(b0 + fb) * S + t) * H + h0 + frw] = ns;  // private line
        }
        // drain our wave's stores, then barrier (compiler also drains at barrier)
        asm volatile("s_waitcnt vmcnt(0)" ::: "memory");
        __syncthreads();

        if (t < S - 1) {
            if (tid == 0) {
                __hip_atomic_fetch_add(flag, 1u, __ATOMIC_RELAXED,
                                       __HIP_MEMORY_SCOPE_AGENT);
                const unsigned target = 32u * (unsigned)(t + 1);
                while (__hip_atomic_load(flag, __ATOMIC_RELAXED,
                                         __HIP_MEMORY_SCOPE_AGENT) < target) {}
            }
            __syncthreads();
        }
        p ^= 1;
    }
}

extern "C" void kernel_launch(void* const* d_in, const int* in_sizes, int n_in,
                              void* d_out, int out_size, void* d_ws, size_t ws_size,
                              hipStream_t stream)
{
    const float* x    = (const float*)d_in[0];   // [32][2048][512]
    const float* Win  = (const float*)d_in[1];   // [1024][512]
    const float* Wres = (const float*)d_in[2];   // [1024][1024]
    float* out = (float*)d_out;                  // [32][2048][1024]

    float* states = (float*)d_ws;                             // 2*32*1024*4 = 262144 B
    unsigned* cnt = (unsigned*)((char*)d_ws + 262144);        // 8 * 256 B

    // zero states (t=0 prev) and barrier counters every launch (graph-replay safe)
    hipMemsetAsync(d_ws, 0, 262144 + 2048, stream);

    // phase 1: u = x @ W_in^T into d_out
    dim3 gemm_grid(1024 / 64, 65536 / 64);
    resv_gemm_uin<<<gemm_grid, 256, 0, stream>>>(x, Win, out, 65536, 1024, 512);

    // phase 2: recurrence (needs 154 KB dynamic LDS)
    constexpr int kLds = (32768 + 4096 + 2048 + 512) * 4;  // 157696 B
    hipFuncSetAttribute((const void*)resv_recur,
                        hipFuncAttributeMaxDynamicSharedMemorySize, kLds);
    resv_recur<<<dim3(256), dim3(256), kLds, stream>>>(Wres, out, states, cnt);
}